// Round 2
// baseline (319.426 us; speedup 1.0000x reference)
//
#include <hip/hip_runtime.h>
#include <math.h>

#define TRAJ_NUM 25
#define T_SAMPLES 10
#define LOS 10
#define G 200
#define VFOV_RAD 0.3490658503988659f   // deg2rad(20)

// thread = (trajectory b, t-sample, half) ; handles 5 LOS points
// total threads = 6400 * 10 * 2 = 128000 = 500 blocks * 256
__global__ __launch_bounds__(256) void trackloss_kernel(
    const float* __restrict__ Df,      // [B,3,3]
    const float* __restrict__ Dp,      // [B,3,3]
    const float* __restrict__ goal,    // [B,3]
    const float* __restrict__ L,       // [6,6]
    const float* __restrict__ sdf,     // [M,200,200,200] (z,y,x)
    const float* __restrict__ minb,    // [M,3]
    const int*   __restrict__ map_id,  // [outer]
    float* __restrict__ out)           // [B]
{
    const int gid  = blockIdx.x * 256 + threadIdx.x;   // 0..127999
    const int b    = gid / 20;
    const int r    = gid % 20;
    const int t_i  = r >> 1;        // 0..9
    const int half = r & 1;         // 0..1
    const int outer = b / TRAJ_NUM;

    const int m = map_id[outer];
    const float gwx = goal[(outer * TRAJ_NUM) * 3 + 0];
    const float gwy = goal[(outer * TRAJ_NUM) * 3 + 1];
    const float gwz = goal[(outer * TRAJ_NUM) * 3 + 2];
    const float mbx = minb[m * 3 + 0];
    const float mby = minb[m * 3 + 1];
    const float mbz = minb[m * 3 + 2];

    // quintic coefficients: coe[c][i] = sum_j L[i][j]*d[c][j]
    float coe[3][6];
    #pragma unroll
    for (int c = 0; c < 3; ++c) {
        float d[6];
        #pragma unroll
        for (int j = 0; j < 3; ++j) {
            d[j]     = Df[b * 9 + c * 3 + j];
            d[j + 3] = Dp[b * 9 + c * 3 + j];
        }
        #pragma unroll
        for (int i = 0; i < 6; ++i) {
            float acc = 0.f;
            #pragma unroll
            for (int j = 0; j < 6; ++j)
                acc += L[i * 6 + j] * d[j];
            coe[c][i] = acc;
        }
    }

    // t = linspace(0.66, 1.32, 10)
    const float t = 0.66f + (float)t_i * (0.66f / 9.0f);

    float p[3], v[3];
    #pragma unroll
    for (int c = 0; c < 3; ++c) {
        float pc = coe[c][5];
        pc = pc * t + coe[c][4];
        pc = pc * t + coe[c][3];
        pc = pc * t + coe[c][2];
        pc = pc * t + coe[c][1];
        pc = pc * t + coe[c][0];
        p[c] = pc;
        float vc = 5.f * coe[c][5];
        vc = vc * t + 4.f * coe[c][4];
        vc = vc * t + 3.f * coe[c][3];
        vc = vc * t + 2.f * coe[c][2];
        vc = vc * t + 1.f * coe[c][1];
        v[c] = vc;
    }

    float val = 0.f;
    if (half == 0) {   // pitch penalty once per (b,t)
        const float gdx = gwx - p[0], gdy = gwy - p[1], gdz = gwz - p[2];
        const float pitch_g = atan2f(gdz, sqrtf(gdx * gdx + gdy * gdy + 1e-6f));
        const float pitch_v = atan2f(v[2], sqrtf(v[0] * v[0] + v[1] * v[1] + 1e-6f));
        val = fmaxf(fabsf(pitch_g - pitch_v) - VFOV_RAD, 0.f) * 0.5f;
    }

    // LOS points s = s0..s0+4 in voxel coords: vox(s) = (p - mb)/0.2 + s * (g-p)/(0.2*9)
    const int s0 = half * 5;
    const float bx = (p[0] - mbx) * 5.0f;          // 1/0.2
    const float by = (p[1] - mby) * 5.0f;
    const float bz = (p[2] - mbz) * 5.0f;
    const float stx = (gwx - p[0]) * (5.0f / 9.0f);
    const float sty = (gwy - p[1]) * (5.0f / 9.0f);
    const float stz = (gwz - p[2]) * (5.0f / 9.0f);

    int   bases[5];
    float fxs[5], fys[5], fzs[5];
    bool  valids[5];
    #pragma unroll
    for (int s = 0; s < 5; ++s) {
        const float si = (float)(s0 + s);
        const float gx = bx + si * stx;
        const float gy = by + si * sty;
        const float gz = bz + si * stz;
        valids[s] = (gx > 0.5f) & (gx < (float)G - 1.5f) &
                    (gy > 0.5f) & (gy < (float)G - 1.5f) &
                    (gz > 0.5f) & (gz < (float)G - 1.5f);
        const int x0 = (int)fminf(fmaxf(floorf(gx), 0.f), (float)(G - 2));
        const int y0 = (int)fminf(fmaxf(floorf(gy), 0.f), (float)(G - 2));
        const int z0 = (int)fminf(fmaxf(floorf(gz), 0.f), (float)(G - 2));
        fxs[s] = gx - (float)x0;
        fys[s] = gy - (float)y0;
        fzs[s] = gz - (float)z0;
        bases[s] = ((m * G + z0) * G + y0) * G + x0;   // < 64M, fits int
    }

    // issue all 40 loads (independent -> deep MLP)
    float c[5][8];
    #pragma unroll
    for (int s = 0; s < 5; ++s) {
        const float* pB = sdf + bases[s];
        c[s][0] = pB[0];
        c[s][1] = pB[1];
        c[s][2] = pB[G];
        c[s][3] = pB[G + 1];
        c[s][4] = pB[G * G];
        c[s][5] = pB[G * G + 1];
        c[s][6] = pB[G * G + G];
        c[s][7] = pB[G * G + G + 1];
    }

    #pragma unroll
    for (int s = 0; s < 5; ++s) {
        const float fx = fxs[s], fy = fys[s], fz = fzs[s];
        const float c0 = (c[s][0] * (1.f - fx) + c[s][1] * fx) * (1.f - fy)
                       + (c[s][2] * (1.f - fx) + c[s][3] * fx) * fy;
        const float c1 = (c[s][4] * (1.f - fx) + c[s][5] * fx) * (1.f - fy)
                       + (c[s][6] * (1.f - fx) + c[s][7] * fx) * fy;
        const float dist = c0 * (1.f - fz) + c1 * fz;
        const float cost = valids[s] ? expf((0.6f - dist) * (1.f / 0.3f)) : 0.f;
        val += fmaxf(0.2f - cost, 0.f) * 0.2f;   // occ contribution, scale 4*5/100
    }

    // combine half-pairs (lanes 2k, 2k+1 share (b,t)), then one atomic per pair
    val += __shfl_xor(val, 1, 64);
    if (half == 0) atomicAdd(&out[b], val);
}

extern "C" void kernel_launch(void* const* d_in, const int* in_sizes, int n_in,
                              void* d_out, int out_size, void* d_ws, size_t ws_size,
                              hipStream_t stream) {
    const float* Df     = (const float*)d_in[0];
    const float* Dp     = (const float*)d_in[1];
    const float* goal   = (const float*)d_in[2];
    const float* L      = (const float*)d_in[3];
    const float* sdf    = (const float*)d_in[4];
    const float* minb   = (const float*)d_in[5];
    const int*   map_id = (const int*)d_in[6];
    float* out = (float*)d_out;

    hipMemsetAsync(out, 0, out_size * sizeof(float), stream);
    trackloss_kernel<<<500, 256, 0, stream>>>(Df, Dp, goal, L, sdf, minb, map_id, out);
}